// Round 9
// baseline (230.631 us; speedup 1.0000x reference)
//
#include <hip/hip_runtime.h>
#include <hip/hip_bf16.h>
#include <math.h>

#define NH 8
#define HD 64
#define CH 512
#define NT 1024
#define NB 8

typedef __bf16 bf16_t;
typedef bf16_t bf16x8 __attribute__((ext_vector_type(8)));
typedef bf16_t bf16x4 __attribute__((ext_vector_type(4)));
typedef float  f32x4  __attribute__((ext_vector_type(4)));
typedef float  f32x16 __attribute__((ext_vector_type(16)));
typedef unsigned u32x4 __attribute__((ext_vector_type(4)));

#define MFMA16(a, b, c) __builtin_amdgcn_mfma_f32_16x16x32_bf16((a), (b), (c), 0, 0, 0)
#define MFMA32(a, b, c) __builtin_amdgcn_mfma_f32_32x32x16_bf16((a), (b), (c), 0, 0, 0)
#define EXP2(x) __builtin_amdgcn_exp2f(x)

__device__ __forceinline__ void gload16(const void* g, void* l) {
    __builtin_amdgcn_global_load_lds(
        (const __attribute__((address_space(1))) void*)g,
        (__attribute__((address_space(3))) void*)l, 16, 0, 0);
}

// pack two f32 -> one dword of 2x bf16 (no builtin on gfx950; T12 recipe)
__device__ __forceinline__ unsigned cvtpk(float lo, float hi) {
    unsigned r;
    asm("v_cvt_pk_bf16_f32 %0, %1, %2" : "=v"(r) : "v"(lo), "v"(hi));
    return r;
}

// v_permlane32_swap_b32: a' = {a.lo32, b.lo32}, b' = {a.hi32, b.hi32}
__device__ __forceinline__ void plswap(unsigned& a, unsigned& b) {
    asm("v_permlane32_swap_b32 %0, %1" : "+v"(a), "+v"(b));
}

// ---------------------------------------------------------------------------
// prep: fp32 [C][N] -> bf16 [N][C] transpose (per 64x64 tile).
// grid (128, 24): x = tile (c-tile = x&7, n-tile = x>>3); y: b = y/3, ft = y%3
// ---------------------------------------------------------------------------
__global__ __launch_bounds__(256) void prep_kernel(
    const float* __restrict__ fc, const float* __restrict__ fp,
    const float* __restrict__ fn, bf16_t* __restrict__ Xc,
    bf16_t* __restrict__ Xn)
{
    __shared__ __align__(16) bf16_t tile[64 * 64];
    const int t = threadIdx.x;
    const int y = blockIdx.y;
    const int b = y / 3, ft = y % 3;
    const int c0 = (blockIdx.x & 7) * 64;
    const int n0 = (blockIdx.x >> 3) * 64;

    const float* src; bf16_t* dst;
    if (ft == 0)      { src = fc + (size_t)b * CH * NT; dst = Xc + (size_t)b * NT * CH; }
    else if (ft == 1) { src = fp + (size_t)b * CH * NT; dst = Xn + (size_t)b * 2 * NT * CH; }
    else              { src = fn + (size_t)b * CH * NT; dst = Xn + (size_t)b * 2 * NT * CH + (size_t)NT * CH; }

    const int nb = t & 15, cb = t >> 4;   // 4-wide chunks
    float4 ld[4];
#pragma unroll
    for (int i = 0; i < 4; ++i)
        ld[i] = *(const float4*)(src + (size_t)(c0 + cb * 4 + i) * NT + n0 + nb * 4);
    const float* lf = (const float*)ld;
#pragma unroll
    for (int j = 0; j < 4; ++j) {
        int n = nb * 4 + j;
        int v = (n >> 2) & 14;            // even -> bf16x8 readback stays contiguous
        bf16x4 wv = { (bf16_t)lf[0 * 4 + j], (bf16_t)lf[1 * 4 + j],
                      (bf16_t)lf[2 * 4 + j], (bf16_t)lf[3 * 4 + j] };
        *(bf16x4*)(tile + n * 64 + ((cb ^ v) * 4)) = wv;
    }
    __syncthreads();
#pragma unroll
    for (int i = 0; i < 2; ++i) {
        int gid = t + i * 256;            // 512 chunks of 16B
        int n = gid >> 3, c16 = gid & 7;
        int v = (n >> 2) & 14;
        bf16x8 val = *(const bf16x8*)(tile + n * 64 + (((2 * c16) ^ v) * 4));
        *(bf16x8*)(dst + (size_t)(n0 + n) * CH + c0 + c16 * 8) = val;
    }
}

// weights fp32 -> bf16, grid (256, 4); also zeroes the LN sum/sumsq buffers
__global__ __launch_bounds__(256) void wcvt_kernel(
    const float* __restrict__ Wq, const float* __restrict__ Wk,
    const float* __restrict__ Wv, const float* __restrict__ Wo,
    bf16_t* __restrict__ Wb, float* __restrict__ SQz)
{
    const int m = blockIdx.y;
    const float* src = (m == 0) ? Wq : (m == 1) ? Wk : (m == 2) ? Wv : Wo;
    bf16_t* dst = Wb + (size_t)m * CH * CH;
    int gid = blockIdx.x * 256 + threadIdx.x;      // 65536 float4 per matrix
    float4 v = *(const float4*)(src + (size_t)gid * 4);
    bf16x4 o = { (bf16_t)v.x, (bf16_t)v.y, (bf16_t)v.z, (bf16_t)v.w };
    *(bf16x4*)(dst + (size_t)gid * 4) = o;
    if (m == 0 && blockIdx.x < 16) {               // 16*256*16B = 64KB (sum+sumsq)
        f32x4 zz = {0.f, 0.f, 0.f, 0.f};
        *(f32x4*)(SQz + (size_t)(blockIdx.x * 256 + threadIdx.x) * 4) = zz;
    }
}

// ---------------------------------------------------------------------------
// gemm_core: 128x128 tile, K=512, BK=32, all-bf16, global_load_lds staging.
// ---------------------------------------------------------------------------
template <bool SWAP>
__device__ __forceinline__ void gemm_core(const bf16_t* __restrict__ A,
                                          const bf16_t* __restrict__ B,
                                          bf16_t* aT, bf16_t* bT,
                                          f32x4 acc[4][4])
{
    const int t = threadIdx.x, w = t >> 6, lane = t & 63;
    const int lid = lane & 15, quad = lane >> 4;
    const int wm = w >> 1, wn = w & 1;
    const int l4 = lane >> 2, k4 = lane & 3;

    for (int kt = 0; kt < 16; ++kt) {
        const int k0 = kt * 32;
        __syncthreads();
#pragma unroll
        for (int i = 0; i < 2; ++i) {
            int q = w * 2 + i;                       // chunk 0..7 (16 rows each)
            int row = q * 16 + l4;
            int kk = k4 ^ ((row >> 1) & 3);
            gload16(A + (size_t)row * CH + k0 + kk * 8, aT + q * 512);
            gload16(B + (size_t)row * CH + k0 + kk * 8, bT + q * 512);
        }
        __syncthreads();

        const bf16_t* mT = SWAP ? bT : aT;
        const bf16_t* nT = SWAP ? aT : bT;
        bf16x8 mf[4], nf[4];
#pragma unroll
        for (int i = 0; i < 4; ++i) {
            int row = wm * 64 + i * 16 + lid;
            int kw = quad ^ ((row >> 1) & 3);
            mf[i] = *(const bf16x8*)(mT + row * 32 + kw * 8);
        }
#pragma unroll
        for (int i = 0; i < 4; ++i) {
            int row = wn * 64 + i * 16 + lid;
            int kw = quad ^ ((row >> 1) & 3);
            nf[i] = *(const bf16x8*)(nT + row * 32 + kw * 8);
        }
#pragma unroll
        for (int mi = 0; mi < 4; ++mi)
#pragma unroll
            for (int ni = 0; ni < 4; ++ni)
                acc[mi][ni] = MFMA16(mf[mi], nf[ni], acc[mi][ni]);
    }
}

// ---------------------------------------------------------------------------
// qkv: grid (160, 8).  bx<32: Q; 32..95: K; 96..159: V (SWAP, writes Vt[co][key])
// ---------------------------------------------------------------------------
__global__ __launch_bounds__(256) void qkv_kernel(
    const bf16_t* __restrict__ Xc, const bf16_t* __restrict__ Xn,
    const bf16_t* __restrict__ Wb,
    bf16_t* __restrict__ Qn, bf16_t* __restrict__ Kn, bf16_t* __restrict__ Vt)
{
    __shared__ __align__(16) bf16_t aT[128 * 32];
    __shared__ __align__(16) bf16_t bT[128 * 32];
    const int bx = blockIdx.x, b = blockIdx.y;
    const int t = threadIdx.x, w = t >> 6, lane = t & 63;
    const int lid = lane & 15, quad = lane >> 4;
    const int wm = w >> 1, wn = w & 1;
    const float QSC = 0.125f * 1.44269504f;

    f32x4 acc[4][4] = {};

    if (bx < 96) {                        // Q or K job
        const bf16_t* A; const bf16_t* B; bf16_t* O; float scale;
        if (bx < 32) {
            int nt = bx >> 2, ct = bx & 3;
            A = Xc + (size_t)b * NT * CH + (size_t)nt * 128 * CH;
            B = Wb + (size_t)0 * CH * CH + (size_t)ct * 128 * CH;
            O = Qn + (size_t)b * NT * CH + (size_t)nt * 128 * CH + ct * 128;
            scale = QSC;
        } else {
            int j = bx - 32, nt = j >> 2, ct = j & 3;
            A = Xn + (size_t)b * 2 * NT * CH + (size_t)nt * 128 * CH;
            B = Wb + (size_t)1 * CH * CH + (size_t)ct * 128 * CH;
            O = Kn + (size_t)b * 2 * NT * CH + (size_t)nt * 128 * CH + ct * 128;
            scale = 1.0f;
        }
        gemm_core<false>(A, B, aT, bT, acc);
#pragma unroll
        for (int mi = 0; mi < 4; ++mi)
#pragma unroll
            for (int ni = 0; ni < 4; ++ni)
#pragma unroll
                for (int r = 0; r < 4; ++r) {
                    int n  = wm * 64 + mi * 16 + quad * 4 + r;
                    int co = wn * 64 + ni * 16 + lid;
                    O[(size_t)n * CH + co] = (bf16_t)(acc[mi][ni][r] * scale);
                }
    } else {                              // V job -> Vt[co][key]
        int j = bx - 96, nt = j >> 2, ct = j & 3;
        const bf16_t* A = Xn + (size_t)b * 2 * NT * CH + (size_t)nt * 128 * CH;
        const bf16_t* B = Wb + (size_t)2 * CH * CH + (size_t)ct * 128 * CH;
        bf16_t* O = Vt + (size_t)b * CH * 2 * NT + (size_t)ct * 128 * 2 * NT + nt * 128;
        gemm_core<true>(A, B, aT, bT, acc);
#pragma unroll
        for (int mi = 0; mi < 4; ++mi)
#pragma unroll
            for (int ni = 0; ni < 4; ++ni)
#pragma unroll
                for (int r = 0; r < 4; ++r) {
                    int co_l  = wm * 64 + mi * 16 + quad * 4 + r;
                    int key_l = wn * 64 + ni * 16 + lid;
                    O[(size_t)co_l * (2 * NT) + key_l] = (bf16_t)acc[mi][ni][r];
                }
    }
}

// ---------------------------------------------------------------------------
// attn v4: register-software-pipelined.
//  - K fragments double-buffered in registers (kfA/kfB, manual 2x unroll so
//    all indexing is static); next-tile K issued mid-body -> ~500cy ahead of
//    its consuming QK^T (covers L2 latency; occupancy is grid-capped 2/CU).
//  - V fragments issued at body top, consumed after QK+softmax (~250cy gap).
//  - per-mf body split keeps s to [2] f32x16 -> peak VGPR ~220 (< 256, so
//    2 waves/SIMD preserved).  Epilogue / LDS / grid unchanged from v3.
// ---------------------------------------------------------------------------
__device__ __forceinline__ void attn_body(
    int kt,
    const bf16_t* __restrict__ Krow, const bf16_t* __restrict__ Vrow,
    const bf16x8 (&qf)[2][4], const bf16x8 (&kfc)[2][4], bf16x8 (&kfn)[2][4],
    f32x16 (&o)[2][2], float (&lpart)[2])
{
    const size_t kb  = (size_t)kt * 128;
    const size_t kbn = (size_t)((kt + 1) & 15) * 128;   // kt=15 prefetch is dead

    // V fragments for current tile (consumed in PV, ~QK+softmax later)
    bf16x8 vf[2][4];
#pragma unroll
    for (int df = 0; df < 2; ++df)
#pragma unroll
        for (int ks = 0; ks < 4; ++ks)
            vf[df][ks] = *(const bf16x8*)(Vrow + (size_t)df * 32 * (2 * NT) + kb + ks * 16);

#pragma unroll
    for (int mf = 0; mf < 2; ++mf) {
        // ---- QK^T for this 32-key half (kfc[mf] prefetched last body) ----
        f32x16 s[2] = {};
        __builtin_amdgcn_s_setprio(1);
#pragma unroll
        for (int ks = 0; ks < 4; ++ks)
#pragma unroll
            for (int nf = 0; nf < 2; ++nf)
                s[nf] = MFMA32(kfc[mf][ks], qf[nf][ks], s[nf]);
        __builtin_amdgcn_s_setprio(0);

        // ---- prefetch next-tile K for this half ---------------------------
#pragma unroll
        for (int ks = 0; ks < 4; ++ks)
            kfn[mf][ks] = *(const bf16x8*)(Krow + (kbn + mf * 32) * CH + ks * 16);

        // ---- softmax in registers -> PV B-fragments -----------------------
        bf16x8 pfrag[2][2];                  // [nf][fi]  fi: 16-key half
#pragma unroll
        for (int nf = 0; nf < 2; ++nf) {
            float p[16];
#pragma unroll
            for (int r = 0; r < 16; ++r) p[r] = EXP2(s[nf][r]);
            lpart[nf] += ((p[0] + p[1]) + (p[2] + p[3]))
                       + ((p[4] + p[5]) + (p[6] + p[7]))
                       + ((p[8] + p[9]) + (p[10] + p[11]))
                       + ((p[12] + p[13]) + (p[14] + p[15]));
            unsigned a0 = cvtpk(p[0], p[1]),   b0 = cvtpk(p[4], p[5]);
            unsigned a1 = cvtpk(p[2], p[3]),   b1 = cvtpk(p[6], p[7]);
            unsigned a2 = cvtpk(p[8], p[9]),   b2 = cvtpk(p[12], p[13]);
            unsigned a3 = cvtpk(p[10], p[11]), b3 = cvtpk(p[14], p[15]);
            plswap(a0, b0); plswap(a1, b1); plswap(a2, b2); plswap(a3, b3);
            u32x4 f0 = { a0, a1, b0, b1 };
            u32x4 f1 = { a2, a3, b2, b3 };
            pfrag[nf][0] = __builtin_bit_cast(bf16x8, f0);
            pfrag[nf][1] = __builtin_bit_cast(bf16x8, f1);
        }

        // ---- PV for this half --------------------------------------------
        __builtin_amdgcn_s_setprio(1);
#pragma unroll
        for (int fi = 0; fi < 2; ++fi) {
            const int ks = mf * 2 + fi;
#pragma unroll
            for (int df = 0; df < 2; ++df)
#pragma unroll
                for (int nf = 0; nf < 2; ++nf)
                    o[df][nf] = MFMA32(vf[df][ks], pfrag[nf][fi], o[df][nf]);
        }
        __builtin_amdgcn_s_setprio(0);
    }
}

__global__ __launch_bounds__(256, 2) void attn_kernel(
    const bf16_t* __restrict__ Qn, const bf16_t* __restrict__ Kn,
    const bf16_t* __restrict__ Vt, bf16_t* __restrict__ AOn)
{
    __shared__ __align__(16) char smem[55808];
    float*  const scr_all = (float*)smem;            // 2 x 4352 f32 (34816B)
    bf16_t* const obuf    = (bf16_t*)(smem + 36864); // [128][72] bf16
    float*  const l_scr   = (float*)(smem + 55296);  // 128 f32

    const int t = threadIdx.x;
    const int w = t >> 6, lane = t & 63;
    const int wq = w >> 1, wk = w & 1;
    const int l31 = lane & 31, h = lane >> 5;

    // XCD-aware decode: all 8 q-tiles of one (b,h) share one XCD's L2.
    const int bid = blockIdx.x;
    const int xcd = bid & 7, ii = bid >> 3;
    const int grp = xcd * 8 + (ii >> 3);
    const int qt  = ii & 7;
    const int b = grp >> 3, hh = grp & 7;
    const int q0 = qt * 128;

    const bf16_t* Qb  = Qn + ((size_t)b * NT + q0) * CH + hh * HD;
    const bf16_t* Kb  = Kn + (size_t)b * 2 * NT * CH + hh * HD;
    const bf16_t* Vtb = Vt + ((size_t)b * CH + hh * HD) * (2 * NT);
    bf16_t* AOb = AOn + ((size_t)b * NT + q0) * CH + hh * HD;

    // per-lane fragment base pointers (16B granules)
    const bf16_t* Qrow = Qb  + (size_t)(wq * 64 + l31) * CH + h * 8;
    const bf16_t* Krow = Kb  + (size_t)(wk * 64 + l31) * CH + h * 8;
    const bf16_t* Vrow = Vtb + (size_t)l31 * (2 * NT) + wk * 64 + h * 8;

    // Q fragments: B-operand, lane(l31=q, h) elem e = Q[q][ks*16 + 8h + e]
    bf16x8 qf[2][4];
#pragma unroll
    for (int nf = 0; nf < 2; ++nf)
#pragma unroll
        for (int ks = 0; ks < 4; ++ks)
            qf[nf][ks] = *(const bf16x8*)(Qrow + (size_t)nf * 32 * CH + ks * 16);

    f32x16 o[2][2] = {};
    float lpart[2] = {0.f, 0.f};

    // prologue: K fragments for tile 0
    bf16x8 kfA[2][4], kfB[2][4];
#pragma unroll
    for (int mf = 0; mf < 2; ++mf)
#pragma unroll
        for (int ks = 0; ks < 4; ++ks)
            kfA[mf][ks] = *(const bf16x8*)(Krow + (size_t)(mf * 32) * CH + ks * 16);

    for (int i = 0; i < 8; ++i) {
        attn_body(2 * i,     Krow, Vrow, qf, kfA, kfB, o, lpart);
        attn_body(2 * i + 1, Krow, Vrow, qf, kfB, kfA, o, lpart);
    }

    // ---- epilogue: combine wk halves, normalize, store --------------------
    float l2[2];
#pragma unroll
    for (int nf = 0; nf < 2; ++nf)
        l2[nf] = lpart[nf] + __shfl_xor(lpart[nf], 32);

    if (wk == 1) {
        float* scr = scr_all + wq * 4352;
#pragma unroll
        for (int df = 0; df < 2; ++df)
#pragma unroll
            for (int nf = 0; nf < 2; ++nf) {
                int qrow = nf * 32 + l31;
#pragma unroll
                for (int g = 0; g < 4; ++g) {
                    int d = df * 32 + 8 * g + 4 * h;
                    f32x4 v = { o[df][nf][4 * g + 0], o[df][nf][4 * g + 1],
                                o[df][nf][4 * g + 2], o[df][nf][4 * g + 3] };
                    *(f32x4*)(scr + qrow * 68 + d) = v;
                }
            }
        if (h == 0) {
            l_scr[wq * 64 + 0 * 32 + l31] = l2[0];
            l_scr[wq * 64 + 1 * 32 + l31] = l2[1];
        }
    }
    __syncthreads();

    if (wk == 0) {
        const float* scr = scr_all + wq * 4352;
        float inv[2];
#pragma unroll
        for (int nf = 0; nf < 2; ++nf)
            inv[nf] = 1.0f / (l2[nf] + l_scr[wq * 64 + nf * 32 + l31]);
#pragma unroll
        for (int df = 0; df < 2; ++df)
#pragma unroll
            for (int nf = 0; nf < 2; ++nf) {
                int qrow = nf * 32 + l31;
#pragma unroll
                for (int g = 0; g < 4; ++g) {
                    int d = df * 32 + 8 * g + 4 * h;
                    f32x4 part = *(const f32x4*)(scr + qrow * 68 + d);
                    bf16x4 ov = {
                        (bf16_t)((o[df][nf][4 * g + 0] + part.x) * inv[nf]),
                        (bf16_t)((o[df][nf][4 * g + 1] + part.y) * inv[nf]),
                        (bf16_t)((o[df][nf][4 * g + 2] + part.z) * inv[nf]),
                        (bf16_t)((o[df][nf][4 * g + 3] + part.w) * inv[nf]) };
                    int qg = wq * 64 + qrow;
                    *(bf16x4*)(obuf + qg * 72 + (d ^ (qg & 24))) = ov;
                }
            }
    }
    __syncthreads();

#pragma unroll
    for (int i = 0; i < 4; ++i) {
        int gid = t + i * 256;
        int qr = gid >> 3, c8 = (gid & 7) * 8;
        *(bf16x8*)(AOb + (size_t)qr * CH + c8) =
            *(const bf16x8*)(obuf + qr * 72 + (c8 ^ (qr & 24)));
    }
}

// ---------------------------------------------------------------------------
// proj: Z^T[b][co][n] = (AO @ Wo^T)^T + f_curr[b][co][n]  (fp32). grid (32, 8)
// Fused LN stats: block reduces its 128-co slab per n, atomicAdd sum/sumsq.
// ---------------------------------------------------------------------------
__global__ __launch_bounds__(256) void proj_kernel(
    const bf16_t* __restrict__ AOn, const bf16_t* __restrict__ Wb,
    const float* __restrict__ fc, float* __restrict__ Zt,
    float* __restrict__ Ssum, float* __restrict__ Ssq)
{
    __shared__ __align__(16) bf16_t aT[128 * 32];
    __shared__ __align__(16) bf16_t bT[128 * 32];
    const int bx = blockIdx.x, b = blockIdx.y;
    const int nt = bx >> 2, ct = bx & 3;
    const int t = threadIdx.x, w = t >> 6, lane = t & 63;
    const int lid = lane & 15, quad = lane >> 4;
    const int wm = w >> 1, wn = w & 1;

    const bf16_t* A = AOn + (size_t)b * NT * CH + (size_t)nt * 128 * CH;
    const bf16_t* B = Wb + (size_t)3 * CH * CH + (size_t)ct * 128 * CH;   // Wo

    f32x4 acc[4][4] = {};
    gemm_core<true>(A, B, aT, bT, acc);

    const size_t bofs = (size_t)b * CH * NT;
    float sP[4] = {0.f, 0.f, 0.f, 0.f}, qP[4] = {0.f, 0.f, 0.f, 0.f};
#pragma unroll
    for (int mi = 0; mi < 4; ++mi)
#pragma unroll
        for (int ni = 0; ni < 4; ++ni)
#pragma unroll
            for (int r = 0; r < 4; ++r) {
                int co_l = wm * 64 + mi * 16 + quad * 4 + r;
                int n_l  = wn * 64 + ni * 16 + lid;
                size_t idx = bofs + (size_t)(ct * 128 + co_l) * NT + nt * 128 + n_l;
                float z = acc[mi][ni][r] + fc[idx];
                Zt[idx] = z;
                sP[ni] += z;
                qP[ni] += z * z;
            }
    // reduce over quad (co sub-blocks) within wave
#pragma unroll
    for (int ni = 0; ni < 4; ++ni) {
        sP[ni] += __shfl_xor(sP[ni], 16);  sP[ni] += __shfl_xor(sP[ni], 32);
        qP[ni] += __shfl_xor(qP[ni], 16);  qP[ni] += __shfl_xor(qP[ni], 32);
    }
    __syncthreads();                      // all frag reads of aT done
    float* sRed = (float*)aT;             // 256 f32
    float* qRed = sRed + 256;
    if (quad == 0) {
#pragma unroll
        for (int ni = 0; ni < 4; ++ni) {
            sRed[w * 64 + ni * 16 + lid] = sP[ni];
            qRed[w * 64 + ni * 16 + lid] = qP[ni];
        }
    }
    __syncthreads();
    if (t < 128) {                        // n_l = t; waves w=wn and w=2+wn
        float s = sRed[t] + sRed[128 + t];
        float q = qRed[t] + qRed[128 + t];
        atomicAdd(&Ssum[(size_t)b * NT + nt * 128 + t], s);
        atomicAdd(&Ssq [(size_t)b * NT + nt * 128 + t], q);
    }
}

// ---------------------------------------------------------------------------
// apply: out[b][co][n] = (z - mu[n]) * rs[n] * gamma[co] + beta[co].
// mu/rs computed inline from fused sum/sumsq.
// ---------------------------------------------------------------------------
__global__ __launch_bounds__(256) void apply_kernel(
    const float* __restrict__ Zt, const float* __restrict__ Ssum,
    const float* __restrict__ Ssq, const float* __restrict__ gamma,
    const float* __restrict__ beta, float* __restrict__ out)
{
    const int row = blockIdx.x;           // b*512 + co
    const int co = row & 511, b = row >> 9;
    const int t = threadIdx.x;
    const float g = gamma[co], be = beta[co];
    const size_t base = (size_t)row * NT + t * 4;
    f32x4 z  = *(const f32x4*)(Zt + base);
    f32x4 S  = *(const f32x4*)(Ssum + (size_t)b * NT + t * 4);
    f32x4 Q2 = *(const f32x4*)(Ssq  + (size_t)b * NT + t * 4);
    f32x4 o;
#pragma unroll
    for (int c = 0; c < 4; ++c) {
        float mu  = S[c] * (1.0f / 512.0f);
        float var = Q2[c] * (1.0f / 512.0f) - mu * mu;
        float rs  = rsqrtf(var + 1e-5f);
        o[c] = (z[c] - mu) * rs * g + be;
    }
    *(f32x4*)(out + base) = o;
}

// ---------------------------------------------------------------------------
extern "C" void kernel_launch(void* const* d_in, const int* in_sizes, int n_in,
                              void* d_out, int out_size, void* d_ws, size_t ws_size,
                              hipStream_t stream)
{
    (void)in_sizes; (void)n_in; (void)out_size; (void)ws_size;
    const float* fc    = (const float*)d_in[0];
    const float* fp    = (const float*)d_in[1];
    const float* fn    = (const float*)d_in[2];
    const float* Wq    = (const float*)d_in[3];
    const float* Wk    = (const float*)d_in[4];
    const float* Wv    = (const float*)d_in[5];
    const float* Wo    = (const float*)d_in[6];
    const float* gamma = (const float*)d_in[7];
    const float* beta  = (const float*)d_in[8];
    float* out = (float*)d_out;

    char* ws = (char*)d_ws;
    bf16_t* Xn  = (bf16_t*)(ws);
    bf16_t* Qn  = (bf16_t*)(ws + 16777216);
    bf16_t* Kn  = (bf16_t*)(ws + 25165824);
    bf16_t* Xc  = (bf16_t*)(ws + 41943040);
    bf16_t* AOn = Xc;
    bf16_t* Vt  = (bf16_t*)(ws + 50331648);
    bf16_t* Wb  = (bf16_t*)(ws + 67108864);
    float*  Ssum = (float*)(ws + 69206016);
    float*  Ssq  = (float*)(ws + 69238784);
    float*  Zt  = (float*)(ws);

    prep_kernel<<<dim3(128, 24), 256, 0, stream>>>(fc, fp, fn, Xc, Xn);
    wcvt_kernel<<<dim3(256, 4), 256, 0, stream>>>(Wq, Wk, Wv, Wo, Wb, Ssum);
    qkv_kernel<<<dim3(160, 8), 256, 0, stream>>>(Xc, Xn, Wb, Qn, Kn, Vt);
    attn_kernel<<<dim3(512), 256, 0, stream>>>(Qn, Kn, Vt, AOn);
    proj_kernel<<<dim3(32, 8), 256, 0, stream>>>(AOn, Wb, fc, Zt, Ssum, Ssq);
    apply_kernel<<<4096, 256, 0, stream>>>(Zt, Ssum, Ssq, gamma, beta, out);
}

// Round 14
// 208.037 us; speedup vs baseline: 1.1086x; 1.1086x over previous
//
#include <hip/hip_runtime.h>
#include <hip/hip_bf16.h>
#include <math.h>

#define NH 8
#define HD 64
#define CH 512
#define NT 1024
#define NB 8

typedef __bf16 bf16_t;
typedef bf16_t bf16x8 __attribute__((ext_vector_type(8)));
typedef bf16_t bf16x4 __attribute__((ext_vector_type(4)));
typedef float  f32x4  __attribute__((ext_vector_type(4)));
typedef float  f32x16 __attribute__((ext_vector_type(16)));
typedef unsigned u32x4 __attribute__((ext_vector_type(4)));

#define MFMA16(a, b, c) __builtin_amdgcn_mfma_f32_16x16x32_bf16((a), (b), (c), 0, 0, 0)
#define MFMA32(a, b, c) __builtin_amdgcn_mfma_f32_32x32x16_bf16((a), (b), (c), 0, 0, 0)
#define EXP2(x) __builtin_amdgcn_exp2f(x)

__device__ __forceinline__ void gload16(const void* g, void* l) {
    __builtin_amdgcn_global_load_lds(
        (const __attribute__((address_space(1))) void*)g,
        (__attribute__((address_space(3))) void*)l, 16, 0, 0);
}

// pack two f32 -> one dword of 2x bf16 (no builtin on gfx950; T12 recipe)
__device__ __forceinline__ unsigned cvtpk(float lo, float hi) {
    unsigned r;
    asm("v_cvt_pk_bf16_f32 %0, %1, %2" : "=v"(r) : "v"(lo), "v"(hi));
    return r;
}

// v_permlane32_swap_b32: a' = {a.lo32, b.lo32}, b' = {a.hi32, b.hi32}
__device__ __forceinline__ void plswap(unsigned& a, unsigned& b) {
    asm("v_permlane32_swap_b32 %0, %1" : "+v"(a), "+v"(b));
}

// ---------------------------------------------------------------------------
// prep: fp32 [C][N] -> bf16 [N][C] transpose (per 64x64 tile).
// grid (128, 24): x = tile (c-tile = x&7, n-tile = x>>3); y: b = y/3, ft = y%3
// ---------------------------------------------------------------------------
__global__ __launch_bounds__(256) void prep_kernel(
    const float* __restrict__ fc, const float* __restrict__ fp,
    const float* __restrict__ fn, bf16_t* __restrict__ Xc,
    bf16_t* __restrict__ Xn)
{
    __shared__ __align__(16) bf16_t tile[64 * 64];
    const int t = threadIdx.x;
    const int y = blockIdx.y;
    const int b = y / 3, ft = y % 3;
    const int c0 = (blockIdx.x & 7) * 64;
    const int n0 = (blockIdx.x >> 3) * 64;

    const float* src; bf16_t* dst;
    if (ft == 0)      { src = fc + (size_t)b * CH * NT; dst = Xc + (size_t)b * NT * CH; }
    else if (ft == 1) { src = fp + (size_t)b * CH * NT; dst = Xn + (size_t)b * 2 * NT * CH; }
    else              { src = fn + (size_t)b * CH * NT; dst = Xn + (size_t)b * 2 * NT * CH + (size_t)NT * CH; }

    const int nb = t & 15, cb = t >> 4;   // 4-wide chunks
    float4 ld[4];
#pragma unroll
    for (int i = 0; i < 4; ++i)
        ld[i] = *(const float4*)(src + (size_t)(c0 + cb * 4 + i) * NT + n0 + nb * 4);
    const float* lf = (const float*)ld;
#pragma unroll
    for (int j = 0; j < 4; ++j) {
        int n = nb * 4 + j;
        int v = (n >> 2) & 14;            // even -> bf16x8 readback stays contiguous
        bf16x4 wv = { (bf16_t)lf[0 * 4 + j], (bf16_t)lf[1 * 4 + j],
                      (bf16_t)lf[2 * 4 + j], (bf16_t)lf[3 * 4 + j] };
        *(bf16x4*)(tile + n * 64 + ((cb ^ v) * 4)) = wv;
    }
    __syncthreads();
#pragma unroll
    for (int i = 0; i < 2; ++i) {
        int gid = t + i * 256;            // 512 chunks of 16B
        int n = gid >> 3, c16 = gid & 7;
        int v = (n >> 2) & 14;
        bf16x8 val = *(const bf16x8*)(tile + n * 64 + (((2 * c16) ^ v) * 4));
        *(bf16x8*)(dst + (size_t)(n0 + n) * CH + c0 + c16 * 8) = val;
    }
}

// weights fp32 -> bf16, grid (256, 4); also zeroes the LN sum/sumsq buffers
__global__ __launch_bounds__(256) void wcvt_kernel(
    const float* __restrict__ Wq, const float* __restrict__ Wk,
    const float* __restrict__ Wv, const float* __restrict__ Wo,
    bf16_t* __restrict__ Wb, float* __restrict__ SQz)
{
    const int m = blockIdx.y;
    const float* src = (m == 0) ? Wq : (m == 1) ? Wk : (m == 2) ? Wv : Wo;
    bf16_t* dst = Wb + (size_t)m * CH * CH;
    int gid = blockIdx.x * 256 + threadIdx.x;      // 65536 float4 per matrix
    float4 v = *(const float4*)(src + (size_t)gid * 4);
    bf16x4 o = { (bf16_t)v.x, (bf16_t)v.y, (bf16_t)v.z, (bf16_t)v.w };
    *(bf16x4*)(dst + (size_t)gid * 4) = o;
    if (m == 0 && blockIdx.x < 16) {               // 16*256*16B = 64KB (sum+sumsq)
        f32x4 zz = {0.f, 0.f, 0.f, 0.f};
        *(f32x4*)(SQz + (size_t)(blockIdx.x * 256 + threadIdx.x) * 4) = zz;
    }
}

// ---------------------------------------------------------------------------
// gemm_core: 128x128 tile, K=512, BK=32, all-bf16, global_load_lds staging.
// ---------------------------------------------------------------------------
template <bool SWAP>
__device__ __forceinline__ void gemm_core(const bf16_t* __restrict__ A,
                                          const bf16_t* __restrict__ B,
                                          bf16_t* aT, bf16_t* bT,
                                          f32x4 acc[4][4])
{
    const int t = threadIdx.x, w = t >> 6, lane = t & 63;
    const int lid = lane & 15, quad = lane >> 4;
    const int wm = w >> 1, wn = w & 1;
    const int l4 = lane >> 2, k4 = lane & 3;

    for (int kt = 0; kt < 16; ++kt) {
        const int k0 = kt * 32;
        __syncthreads();
#pragma unroll
        for (int i = 0; i < 2; ++i) {
            int q = w * 2 + i;                       // chunk 0..7 (16 rows each)
            int row = q * 16 + l4;
            int kk = k4 ^ ((row >> 1) & 3);
            gload16(A + (size_t)row * CH + k0 + kk * 8, aT + q * 512);
            gload16(B + (size_t)row * CH + k0 + kk * 8, bT + q * 512);
        }
        __syncthreads();

        const bf16_t* mT = SWAP ? bT : aT;
        const bf16_t* nT = SWAP ? aT : bT;
        bf16x8 mf[4], nf[4];
#pragma unroll
        for (int i = 0; i < 4; ++i) {
            int row = wm * 64 + i * 16 + lid;
            int kw = quad ^ ((row >> 1) & 3);
            mf[i] = *(const bf16x8*)(mT + row * 32 + kw * 8);
        }
#pragma unroll
        for (int i = 0; i < 4; ++i) {
            int row = wn * 64 + i * 16 + lid;
            int kw = quad ^ ((row >> 1) & 3);
            nf[i] = *(const bf16x8*)(nT + row * 32 + kw * 8);
        }
#pragma unroll
        for (int mi = 0; mi < 4; ++mi)
#pragma unroll
            for (int ni = 0; ni < 4; ++ni)
                acc[mi][ni] = MFMA16(mf[mi], nf[ni], acc[mi][ni]);
    }
}

// ---------------------------------------------------------------------------
// qkv: grid (160, 8).  bx<32: Q; 32..95: K; 96..159: V (SWAP, writes Vt[co][key])
// ---------------------------------------------------------------------------
__global__ __launch_bounds__(256) void qkv_kernel(
    const bf16_t* __restrict__ Xc, const bf16_t* __restrict__ Xn,
    const bf16_t* __restrict__ Wb,
    bf16_t* __restrict__ Qn, bf16_t* __restrict__ Kn, bf16_t* __restrict__ Vt)
{
    __shared__ __align__(16) bf16_t aT[128 * 32];
    __shared__ __align__(16) bf16_t bT[128 * 32];
    const int bx = blockIdx.x, b = blockIdx.y;
    const int t = threadIdx.x, w = t >> 6, lane = t & 63;
    const int lid = lane & 15, quad = lane >> 4;
    const int wm = w >> 1, wn = w & 1;
    const float QSC = 0.125f * 1.44269504f;

    f32x4 acc[4][4] = {};

    if (bx < 96) {                        // Q or K job
        const bf16_t* A; const bf16_t* B; bf16_t* O; float scale;
        if (bx < 32) {
            int nt = bx >> 2, ct = bx & 3;
            A = Xc + (size_t)b * NT * CH + (size_t)nt * 128 * CH;
            B = Wb + (size_t)0 * CH * CH + (size_t)ct * 128 * CH;
            O = Qn + (size_t)b * NT * CH + (size_t)nt * 128 * CH + ct * 128;
            scale = QSC;
        } else {
            int j = bx - 32, nt = j >> 2, ct = j & 3;
            A = Xn + (size_t)b * 2 * NT * CH + (size_t)nt * 128 * CH;
            B = Wb + (size_t)1 * CH * CH + (size_t)ct * 128 * CH;
            O = Kn + (size_t)b * 2 * NT * CH + (size_t)nt * 128 * CH + ct * 128;
            scale = 1.0f;
        }
        gemm_core<false>(A, B, aT, bT, acc);
#pragma unroll
        for (int mi = 0; mi < 4; ++mi)
#pragma unroll
            for (int ni = 0; ni < 4; ++ni)
#pragma unroll
                for (int r = 0; r < 4; ++r) {
                    int n  = wm * 64 + mi * 16 + quad * 4 + r;
                    int co = wn * 64 + ni * 16 + lid;
                    O[(size_t)n * CH + co] = (bf16_t)(acc[mi][ni][r] * scale);
                }
    } else {                              // V job -> Vt[co][key]
        int j = bx - 96, nt = j >> 2, ct = j & 3;
        const bf16_t* A = Xn + (size_t)b * 2 * NT * CH + (size_t)nt * 128 * CH;
        const bf16_t* B = Wb + (size_t)2 * CH * CH + (size_t)ct * 128 * CH;
        bf16_t* O = Vt + (size_t)b * CH * 2 * NT + (size_t)ct * 128 * 2 * NT + nt * 128;
        gemm_core<true>(A, B, aT, bT, acc);
#pragma unroll
        for (int mi = 0; mi < 4; ++mi)
#pragma unroll
            for (int ni = 0; ni < 4; ++ni)
#pragma unroll
                for (int r = 0; r < 4; ++r) {
                    int co_l  = wm * 64 + mi * 16 + quad * 4 + r;
                    int key_l = wn * 64 + ni * 16 + lid;
                    O[(size_t)co_l * (2 * NT) + key_l] = (bf16_t)acc[mi][ni][r];
                }
    }
}

// ---------------------------------------------------------------------------
// attn v5a: coalesced global_load_lds staging of K/V (L1-gather fix).
// v3/v4 were L1-request-bound: fragment gathers touch 32 lines/instr.
// v5 stages K [128key][64d] and V^T [64d][128key] tiles into LDS with
// gload16 (4 lines/instr, no VGPR roundtrip, no staging VALU), reads
// fragments via XOR-swizzled ds_read_b128 (pre-swizzled global source,
// linear LDS dest -- same pattern as gemm_core). Double-buffered, ONE
// barrier per k-tile; loads issued before compute so the pre-barrier
// vmcnt drain is covered. LDS 64KB -> 2 blocks/CU.
// v5a fix: scalar LDS pointers (hipcc rejects const ARRAYS of
// addrspace(3)-cast pointers: "unsupported expression in static
// initializer"); buffer selected via ternary on cur.
// ---------------------------------------------------------------------------
__global__ __launch_bounds__(256, 2) void attn_kernel(
    const bf16_t* __restrict__ Qn, const bf16_t* __restrict__ Kn,
    const bf16_t* __restrict__ Vt, bf16_t* __restrict__ AOn)
{
    __shared__ __align__(16) char smem[65536];
    bf16_t* const kbuf0 = (bf16_t*)smem;             // [128][64] bf16
    bf16_t* const kbuf1 = (bf16_t*)(smem + 16384);
    bf16_t* const vbuf0 = (bf16_t*)(smem + 32768);   // [64][128] bf16
    bf16_t* const vbuf1 = (bf16_t*)(smem + 49152);
    // epilogue overlays (used only after the main loop's final barrier):
    float*  const scr_all = (float*)smem;            // 2 x 4352 f32 (34816B)
    bf16_t* const obuf    = (bf16_t*)(smem + 36864); // [128][72] bf16
    float*  const l_scr   = (float*)(smem + 55296);  // 128 f32

    const int t = threadIdx.x;
    const int w = t >> 6, lane = t & 63;
    const int wq = w >> 1, wk = w & 1;
    const int l31 = lane & 31, h = lane >> 5;

    // XCD-aware decode: all 8 q-tiles of one (b,h) share one XCD's L2.
    const int bid = blockIdx.x;
    const int xcd = bid & 7, ii = bid >> 3;
    const int grp = xcd * 8 + (ii >> 3);
    const int qt  = ii & 7;
    const int b = grp >> 3, hh = grp & 7;
    const int q0 = qt * 128;

    const bf16_t* Qb  = Qn + ((size_t)b * NT + q0) * CH + hh * HD;
    const bf16_t* Kb  = Kn + (size_t)b * 2 * NT * CH + hh * HD;
    const bf16_t* Vtb = Vt + ((size_t)b * CH + hh * HD) * (2 * NT);
    bf16_t* AOb = AOn + ((size_t)b * NT + q0) * CH + hh * HD;

    // ---- staging (all 4 waves): K tile 1024 chunks, V tile 1024 chunks ----
    // K LDS [128 key][64 d]: chunk c -> row c>>3, granule c&7; src granule
    // pre-swizzled by (row&7).  V LDS [64 d][128 key]: row c>>4, gran c&15,
    // swizzled by (row&15).  LDS dest is wave-uniform base (lane-linear).
#define STAGE_KV(kbn, kw, vw)                                                  \
    {                                                                          \
        _Pragma("unroll")                                                      \
        for (int i = 0; i < 4; ++i) {                                          \
            int ck = w * 64 + i * 256 + lane;                                  \
            int kr = ck >> 3, kg = ck & 7;                                     \
            gload16(Kb + (size_t)((kbn) + kr) * CH + ((kg ^ (kr & 7)) * 8),    \
                    (kw) + (w * 64 + i * 256) * 8);                            \
            int cv = ck;                                                       \
            int vr = cv >> 4, vg = cv & 15;                                    \
            gload16(Vtb + (size_t)vr * (2 * NT) + (kbn) + ((vg ^ (vr & 15)) * 8), \
                    (vw) + (w * 64 + i * 256) * 8);                            \
        }                                                                      \
    }

    // Q fragments: gathered once (one-time cost).
    const bf16_t* Qrow = Qb + (size_t)(wq * 64 + l31) * CH + h * 8;
    bf16x8 qf[2][4];
#pragma unroll
    for (int nf = 0; nf < 2; ++nf)
#pragma unroll
        for (int ks = 0; ks < 4; ++ks)
            qf[nf][ks] = *(const bf16x8*)(Qrow + (size_t)nf * 32 * CH + ks * 16);

    // prologue: stage tile 0 into buf 0
    STAGE_KV(0, kbuf0, vbuf0);
    __syncthreads();

    f32x16 o[2][2] = {};
    float lpart[2] = {0.f, 0.f};

    const int swk = l31 & 7;     // K read swizzle (row&7 == l31&7)
    const int swv = l31 & 15;    // V read swizzle (row&15 == l31&15)

    for (int kt = 0; kt < 16; ++kt) {
        const int cur = kt & 1;
        const bf16_t* const kr_buf = cur ? kbuf1 : kbuf0;
        const bf16_t* const vr_buf = cur ? vbuf1 : vbuf0;
        bf16_t* const kw_buf = cur ? kbuf0 : kbuf1;
        bf16_t* const vw_buf = cur ? vbuf0 : vbuf1;

        // issue next tile's staging first (lands during compute below)
        if (kt < 15)
            STAGE_KV((kt + 1) * 128, kw_buf, vw_buf);

#pragma unroll
        for (int mf = 0; mf < 2; ++mf) {
            // ---- K fragments from LDS (swizzled b128 reads) --------------
            const int krow = wk * 64 + mf * 32 + l31;
            bf16x8 kfm[4];
#pragma unroll
            for (int ks = 0; ks < 4; ++ks)
                kfm[ks] = *(const bf16x8*)(kr_buf + krow * 64 + (((ks * 2 + h) ^ swk) * 8));

            f32x16 s[2] = {};
            __builtin_amdgcn_s_setprio(1);
#pragma unroll
            for (int ks = 0; ks < 4; ++ks)
#pragma unroll
                for (int nf = 0; nf < 2; ++nf)
                    s[nf] = MFMA32(kfm[ks], qf[nf][ks], s[nf]);
            __builtin_amdgcn_s_setprio(0);

            // ---- softmax in registers -> PV B-fragments ------------------
            bf16x8 pfrag[2][2];                  // [nf][fi]
#pragma unroll
            for (int nf = 0; nf < 2; ++nf) {
                float p[16];
#pragma unroll
                for (int r = 0; r < 16; ++r) p[r] = EXP2(s[nf][r]);
                lpart[nf] += ((p[0] + p[1]) + (p[2] + p[3]))
                           + ((p[4] + p[5]) + (p[6] + p[7]))
                           + ((p[8] + p[9]) + (p[10] + p[11]))
                           + ((p[12] + p[13]) + (p[14] + p[15]));
                unsigned a0 = cvtpk(p[0], p[1]),   b0 = cvtpk(p[4], p[5]);
                unsigned a1 = cvtpk(p[2], p[3]),   b1 = cvtpk(p[6], p[7]);
                unsigned a2 = cvtpk(p[8], p[9]),   b2 = cvtpk(p[12], p[13]);
                unsigned a3 = cvtpk(p[10], p[11]), b3 = cvtpk(p[14], p[15]);
                plswap(a0, b0); plswap(a1, b1); plswap(a2, b2); plswap(a3, b3);
                u32x4 f0 = { a0, a1, b0, b1 };
                u32x4 f1 = { a2, a3, b2, b3 };
                pfrag[nf][0] = __builtin_bit_cast(bf16x8, f0);
                pfrag[nf][1] = __builtin_bit_cast(bf16x8, f1);
            }

            // ---- PV for this half (V fragments from LDS) ------------------
            __builtin_amdgcn_s_setprio(1);
#pragma unroll
            for (int fi = 0; fi < 2; ++fi) {
                const int ks = mf * 2 + fi;
                bf16x8 av[2];
#pragma unroll
                for (int df = 0; df < 2; ++df) {
                    int vrow = df * 32 + l31;
                    av[df] = *(const bf16x8*)(vr_buf + vrow * 128 +
                             (((wk * 8 + ks * 2 + h) ^ swv) * 8));
                }
#pragma unroll
                for (int df = 0; df < 2; ++df)
#pragma unroll
                    for (int nf = 0; nf < 2; ++nf)
                        o[df][nf] = MFMA32(av[df], pfrag[nf][fi], o[df][nf]);
            }
            __builtin_amdgcn_s_setprio(0);
        }
        __syncthreads();   // drains next-tile gloads; LDS bufs swap safely
    }
#undef STAGE_KV

    // ---- epilogue: combine wk halves, normalize, store --------------------
    float l2[2];
#pragma unroll
    for (int nf = 0; nf < 2; ++nf)
        l2[nf] = lpart[nf] + __shfl_xor(lpart[nf], 32);

    if (wk == 1) {
        float* scr = scr_all + wq * 4352;
#pragma unroll
        for (int df = 0; df < 2; ++df)
#pragma unroll
            for (int nf = 0; nf < 2; ++nf) {
                int qrow = nf * 32 + l31;
#pragma unroll
                for (int g = 0; g < 4; ++g) {
                    int d = df * 32 + 8 * g + 4 * h;
                    f32x4 v = { o[df][nf][4 * g + 0], o[df][nf][4 * g + 1],
                                o[df][nf][4 * g + 2], o[df][nf][4 * g + 3] };
                    *(f32x4*)(scr + qrow * 68 + d) = v;
                }
            }
        if (h == 0) {
            l_scr[wq * 64 + 0 * 32 + l31] = l2[0];
            l_scr[wq * 64 + 1 * 32 + l31] = l2[1];
        }
    }
    __syncthreads();

    if (wk == 0) {
        const float* scr = scr_all + wq * 4352;
        float inv[2];
#pragma unroll
        for (int nf = 0; nf < 2; ++nf)
            inv[nf] = 1.0f / (l2[nf] + l_scr[wq * 64 + nf * 32 + l31]);
#pragma unroll
        for (int df = 0; df < 2; ++df)
#pragma unroll
            for (int nf = 0; nf < 2; ++nf) {
                int qrow = nf * 32 + l31;
#pragma unroll
                for (int g = 0; g < 4; ++g) {
                    int d = df * 32 + 8 * g + 4 * h;
                    f32x4 part = *(const f32x4*)(scr + qrow * 68 + d);
                    bf16x4 ov = {
                        (bf16_t)((o[df][nf][4 * g + 0] + part.x) * inv[nf]),
                        (bf16_t)((o[df][nf][4 * g + 1] + part.y) * inv[nf]),
                        (bf16_t)((o[df][nf][4 * g + 2] + part.z) * inv[nf]),
                        (bf16_t)((o[df][nf][4 * g + 3] + part.w) * inv[nf]) };
                    int qg = wq * 64 + qrow;
                    *(bf16x4*)(obuf + qg * 72 + (d ^ (qg & 24))) = ov;
                }
            }
    }
    __syncthreads();

#pragma unroll
    for (int i = 0; i < 4; ++i) {
        int gid = t + i * 256;
        int qr = gid >> 3, c8 = (gid & 7) * 8;
        *(bf16x8*)(AOb + (size_t)qr * CH + c8) =
            *(const bf16x8*)(obuf + qr * 72 + (c8 ^ (qr & 24)));
    }
}

// ---------------------------------------------------------------------------
// proj: Z^T[b][co][n] = (AO @ Wo^T)^T + f_curr[b][co][n]  (fp32). grid (32, 8)
// Fused LN stats: block reduces its 128-co slab per n, atomicAdd sum/sumsq.
// ---------------------------------------------------------------------------
__global__ __launch_bounds__(256) void proj_kernel(
    const bf16_t* __restrict__ AOn, const bf16_t* __restrict__ Wb,
    const float* __restrict__ fc, float* __restrict__ Zt,
    float* __restrict__ Ssum, float* __restrict__ Ssq)
{
    __shared__ __align__(16) bf16_t aT[128 * 32];
    __shared__ __align__(16) bf16_t bT[128 * 32];
    const int bx = blockIdx.x, b = blockIdx.y;
    const int nt = bx >> 2, ct = bx & 3;
    const int t = threadIdx.x, w = t >> 6, lane = t & 63;
    const int lid = lane & 15, quad = lane >> 4;
    const int wm = w >> 1, wn = w & 1;

    const bf16_t* A = AOn + (size_t)b * NT * CH + (size_t)nt * 128 * CH;
    const bf16_t* B = Wb + (size_t)3 * CH * CH + (size_t)ct * 128 * CH;   // Wo

    f32x4 acc[4][4] = {};
    gemm_core<true>(A, B, aT, bT, acc);

    const size_t bofs = (size_t)b * CH * NT;
    float sP[4] = {0.f, 0.f, 0.f, 0.f}, qP[4] = {0.f, 0.f, 0.f, 0.f};
#pragma unroll
    for (int mi = 0; mi < 4; ++mi)
#pragma unroll
        for (int ni = 0; ni < 4; ++ni)
#pragma unroll
            for (int r = 0; r < 4; ++r) {
                int co_l = wm * 64 + mi * 16 + quad * 4 + r;
                int n_l  = wn * 64 + ni * 16 + lid;
                size_t idx = bofs + (size_t)(ct * 128 + co_l) * NT + nt * 128 + n_l;
                float z = acc[mi][ni][r] + fc[idx];
                Zt[idx] = z;
                sP[ni] += z;
                qP[ni] += z * z;
            }
    // reduce over quad (co sub-blocks) within wave
#pragma unroll
    for (int ni = 0; ni < 4; ++ni) {
        sP[ni] += __shfl_xor(sP[ni], 16);  sP[ni] += __shfl_xor(sP[ni], 32);
        qP[ni] += __shfl_xor(qP[ni], 16);  qP[ni] += __shfl_xor(qP[ni], 32);
    }
    __syncthreads();                      // all frag reads of aT done
    float* sRed = (float*)aT;             // 256 f32
    float* qRed = sRed + 256;
    if (quad == 0) {
#pragma unroll
        for (int ni = 0; ni < 4; ++ni) {
            sRed[w * 64 + ni * 16 + lid] = sP[ni];
            qRed[w * 64 + ni * 16 + lid] = qP[ni];
        }
    }
    __syncthreads();
    if (t < 128) {                        // n_l = t; waves w=wn and w=2+wn
        float s = sRed[t] + sRed[128 + t];
        float q = qRed[t] + qRed[128 + t];
        atomicAdd(&Ssum[(size_t)b * NT + nt * 128 + t], s);
        atomicAdd(&Ssq [(size_t)b * NT + nt * 128 + t], q);
    }
}

// ---------------------------------------------------------------------------
// apply: out[b][co][n] = (z - mu[n]) * rs[n] * gamma[co] + beta[co].
// mu/rs computed inline from fused sum/sumsq.
// ---------------------------------------------------------------------------
__global__ __launch_bounds__(256) void apply_kernel(
    const float* __restrict__ Zt, const float* __restrict__ Ssum,
    const float* __restrict__ Ssq, const float* __restrict__ gamma,
    const float* __restrict__ beta, float* __restrict__ out)
{
    const int row = blockIdx.x;           // b*512 + co
    const int co = row & 511, b = row >> 9;
    const int t = threadIdx.x;
    const float g = gamma[co], be = beta[co];
    const size_t base = (size_t)row * NT + t * 4;
    f32x4 z  = *(const f32x4*)(Zt + base);
    f32x4 S  = *(const f32x4*)(Ssum + (size_t)b * NT + t * 4);
    f32x4 Q2 = *(const f32x4*)(Ssq  + (size_t)b * NT + t * 4);
    f32x4 o;
#pragma unroll
    for (int c = 0; c < 4; ++c) {
        float mu  = S[c] * (1.0f / 512.0f);
        float var = Q2[c] * (1.0f / 512.0f) - mu * mu;
        float rs  = rsqrtf(var + 1e-5f);
        o[c] = (z[c] - mu) * rs * g + be;
    }
    *(f32x4*)(out + base) = o;
}

// ---------------------------------------------------------------------------
extern "C" void kernel_launch(void* const* d_in, const int* in_sizes, int n_in,
                              void* d_out, int out_size, void* d_ws, size_t ws_size,
                              hipStream_t stream)
{
    (void)in_sizes; (void)n_in; (void)out_size; (void)ws_size;
    const float* fc    = (const float*)d_in[0];
    const float* fp    = (const float*)d_in[1];
    const float* fn    = (const float*)d_in[2];
    const float* Wq    = (const float*)d_in[3];
    const float* Wk    = (const float*)d_in[4];
    const float* Wv    = (const float*)d_in[5];
    const float* Wo    = (const float*)d_in[6];
    const float* gamma = (const float*)d_in[7];
    const float* beta  = (const float*)d_in[8];
    float* out = (float*)d_out;

    char* ws = (char*)d_ws;
    bf16_t* Xn  = (bf16_t*)(ws);
    bf16_t* Qn  = (bf16_t*)(ws + 16777216);
    bf16_t* Kn  = (bf16_t*)(ws + 25165824);
    bf16_t* Xc  = (bf16_t*)(ws + 41943040);
    bf16_t* AOn = Xc;
    bf16_t* Vt  = (bf16_t*)(ws + 50331648);
    bf16_t* Wb  = (bf16_t*)(ws + 67108864);
    float*  Ssum = (float*)(ws + 69206016);
    float*  Ssq  = (float*)(ws + 69238784);
    float*  Zt  = (float*)(ws);

    prep_kernel<<<dim3(128, 24), 256, 0, stream>>>(fc, fp, fn, Xc, Xn);
    wcvt_kernel<<<dim3(256, 4), 256, 0, stream>>>(Wq, Wk, Wv, Wo, Wb, Ssum);
    qkv_kernel<<<dim3(160, 8), 256, 0, stream>>>(Xc, Xn, Wb, Qn, Kn, Vt);
    attn_kernel<<<dim3(512), 256, 0, stream>>>(Qn, Kn, Vt, AOn);
    proj_kernel<<<dim3(32, 8), 256, 0, stream>>>(AOn, Wb, fc, Zt, Ssum, Ssq);
    apply_kernel<<<4096, 256, 0, stream>>>(Zt, Ssum, Ssq, gamma, beta, out);
}

// Round 15
// 207.474 us; speedup vs baseline: 1.1116x; 1.0027x over previous
//
#include <hip/hip_runtime.h>
#include <hip/hip_bf16.h>
#include <math.h>

#define NH 8
#define HD 64
#define CH 512
#define NT 1024
#define NB 8

typedef __bf16 bf16_t;
typedef bf16_t bf16x8 __attribute__((ext_vector_type(8)));
typedef bf16_t bf16x4 __attribute__((ext_vector_type(4)));
typedef float  f32x4  __attribute__((ext_vector_type(4)));
typedef float  f32x16 __attribute__((ext_vector_type(16)));
typedef unsigned u32x4 __attribute__((ext_vector_type(4)));

#define MFMA16(a, b, c) __builtin_amdgcn_mfma_f32_16x16x32_bf16((a), (b), (c), 0, 0, 0)
#define MFMA32(a, b, c) __builtin_amdgcn_mfma_f32_32x32x16_bf16((a), (b), (c), 0, 0, 0)
#define EXP2(x) __builtin_amdgcn_exp2f(x)

__device__ __forceinline__ void gload16(const void* g, void* l) {
    __builtin_amdgcn_global_load_lds(
        (const __attribute__((address_space(1))) void*)g,
        (__attribute__((address_space(3))) void*)l, 16, 0, 0);
}

// pack two f32 -> one dword of 2x bf16 (no builtin on gfx950; T12 recipe)
__device__ __forceinline__ unsigned cvtpk(float lo, float hi) {
    unsigned r;
    asm("v_cvt_pk_bf16_f32 %0, %1, %2" : "=v"(r) : "v"(lo), "v"(hi));
    return r;
}

// v_permlane32_swap_b32: a' = {a.lo32, b.lo32}, b' = {a.hi32, b.hi32}
__device__ __forceinline__ void plswap(unsigned& a, unsigned& b) {
    asm("v_permlane32_swap_b32 %0, %1" : "+v"(a), "+v"(b));
}

// ---------------------------------------------------------------------------
// prep: fp32 [C][N] -> bf16 [N][C] transpose (per 64x64 tile).
// grid (128, 24): x = tile (c-tile = x&7, n-tile = x>>3); y: b = y/3, ft = y%3
// ---------------------------------------------------------------------------
__global__ __launch_bounds__(256) void prep_kernel(
    const float* __restrict__ fc, const float* __restrict__ fp,
    const float* __restrict__ fn, bf16_t* __restrict__ Xc,
    bf16_t* __restrict__ Xn)
{
    __shared__ __align__(16) bf16_t tile[64 * 64];
    const int t = threadIdx.x;
    const int y = blockIdx.y;
    const int b = y / 3, ft = y % 3;
    const int c0 = (blockIdx.x & 7) * 64;
    const int n0 = (blockIdx.x >> 3) * 64;

    const float* src; bf16_t* dst;
    if (ft == 0)      { src = fc + (size_t)b * CH * NT; dst = Xc + (size_t)b * NT * CH; }
    else if (ft == 1) { src = fp + (size_t)b * CH * NT; dst = Xn + (size_t)b * 2 * NT * CH; }
    else              { src = fn + (size_t)b * CH * NT; dst = Xn + (size_t)b * 2 * NT * CH + (size_t)NT * CH; }

    const int nb = t & 15, cb = t >> 4;   // 4-wide chunks
    float4 ld[4];
#pragma unroll
    for (int i = 0; i < 4; ++i)
        ld[i] = *(const float4*)(src + (size_t)(c0 + cb * 4 + i) * NT + n0 + nb * 4);
    const float* lf = (const float*)ld;
#pragma unroll
    for (int j = 0; j < 4; ++j) {
        int n = nb * 4 + j;
        int v = (n >> 2) & 14;            // even -> bf16x8 readback stays contiguous
        bf16x4 wv = { (bf16_t)lf[0 * 4 + j], (bf16_t)lf[1 * 4 + j],
                      (bf16_t)lf[2 * 4 + j], (bf16_t)lf[3 * 4 + j] };
        *(bf16x4*)(tile + n * 64 + ((cb ^ v) * 4)) = wv;
    }
    __syncthreads();
#pragma unroll
    for (int i = 0; i < 2; ++i) {
        int gid = t + i * 256;            // 512 chunks of 16B
        int n = gid >> 3, c16 = gid & 7;
        int v = (n >> 2) & 14;
        bf16x8 val = *(const bf16x8*)(tile + n * 64 + (((2 * c16) ^ v) * 4));
        *(bf16x8*)(dst + (size_t)(n0 + n) * CH + c0 + c16 * 8) = val;
    }
}

// weights fp32 -> bf16, grid (256, 4); also zeroes the LN sum/sumsq buffers
__global__ __launch_bounds__(256) void wcvt_kernel(
    const float* __restrict__ Wq, const float* __restrict__ Wk,
    const float* __restrict__ Wv, const float* __restrict__ Wo,
    bf16_t* __restrict__ Wb, float* __restrict__ SQz)
{
    const int m = blockIdx.y;
    const float* src = (m == 0) ? Wq : (m == 1) ? Wk : (m == 2) ? Wv : Wo;
    bf16_t* dst = Wb + (size_t)m * CH * CH;
    int gid = blockIdx.x * 256 + threadIdx.x;      // 65536 float4 per matrix
    float4 v = *(const float4*)(src + (size_t)gid * 4);
    bf16x4 o = { (bf16_t)v.x, (bf16_t)v.y, (bf16_t)v.z, (bf16_t)v.w };
    *(bf16x4*)(dst + (size_t)gid * 4) = o;
    if (m == 0 && blockIdx.x < 16) {               // 16*256*16B = 64KB (sum+sumsq)
        f32x4 zz = {0.f, 0.f, 0.f, 0.f};
        *(f32x4*)(SQz + (size_t)(blockIdx.x * 256 + threadIdx.x) * 4) = zz;
    }
}

// ---------------------------------------------------------------------------
// gemm_core v6: 128x128 tile, K=512, BK=32, double-buffered LDS staging --
// ONE barrier per K-step (v5a schedule): stage(kt+1) issued first, compute
// on buf[kt&1], barrier drains gloads + protects buffer reuse.
// LDS: 4 x 8KB buffers = 32KB.
// ---------------------------------------------------------------------------
template <bool SWAP>
__device__ __forceinline__ void gemm_core(const bf16_t* __restrict__ A,
                                          const bf16_t* __restrict__ B,
                                          bf16_t* aT0, bf16_t* bT0,
                                          bf16_t* aT1, bf16_t* bT1,
                                          f32x4 acc[4][4])
{
    const int t = threadIdx.x, w = t >> 6, lane = t & 63;
    const int lid = lane & 15, quad = lane >> 4;
    const int wm = w >> 1, wn = w & 1;
    const int l4 = lane >> 2, k4 = lane & 3;

#define GSTAGE(k0, aT, bT)                                                     \
    {                                                                          \
        _Pragma("unroll")                                                      \
        for (int i = 0; i < 2; ++i) {                                          \
            int q = w * 2 + i;                       /* chunk 0..7 */          \
            int row = q * 16 + l4;                                             \
            int kk = k4 ^ ((row >> 1) & 3);                                    \
            gload16(A + (size_t)row * CH + (k0) + kk * 8, (aT) + q * 512);     \
            gload16(B + (size_t)row * CH + (k0) + kk * 8, (bT) + q * 512);     \
        }                                                                      \
    }

    GSTAGE(0, aT0, bT0);
    __syncthreads();

    for (int kt = 0; kt < 16; ++kt) {
        const int cur = kt & 1;
        const bf16_t* aTr = cur ? aT1 : aT0;
        const bf16_t* bTr = cur ? bT1 : bT0;
        if (kt < 15) {
            bf16_t* aTw = cur ? aT0 : aT1;
            bf16_t* bTw = cur ? bT0 : bT1;
            GSTAGE((kt + 1) * 32, aTw, bTw);
        }

        const bf16_t* mT = SWAP ? bTr : aTr;
        const bf16_t* nT = SWAP ? aTr : bTr;
        bf16x8 mf[4], nf[4];
#pragma unroll
        for (int i = 0; i < 4; ++i) {
            int row = wm * 64 + i * 16 + lid;
            int kw = quad ^ ((row >> 1) & 3);
            mf[i] = *(const bf16x8*)(mT + row * 32 + kw * 8);
        }
#pragma unroll
        for (int i = 0; i < 4; ++i) {
            int row = wn * 64 + i * 16 + lid;
            int kw = quad ^ ((row >> 1) & 3);
            nf[i] = *(const bf16x8*)(nT + row * 32 + kw * 8);
        }
        __builtin_amdgcn_s_setprio(1);
#pragma unroll
        for (int mi = 0; mi < 4; ++mi)
#pragma unroll
            for (int ni = 0; ni < 4; ++ni)
                acc[mi][ni] = MFMA16(mf[mi], nf[ni], acc[mi][ni]);
        __builtin_amdgcn_s_setprio(0);
        __syncthreads();   // drains next-tile gloads; buffers swap safely
    }
#undef GSTAGE
}

// ---------------------------------------------------------------------------
// qkv: grid (160, 8).  bx<32: Q; 32..95: K; 96..159: V (SWAP, writes Vt[co][key])
// ---------------------------------------------------------------------------
__global__ __launch_bounds__(256) void qkv_kernel(
    const bf16_t* __restrict__ Xc, const bf16_t* __restrict__ Xn,
    const bf16_t* __restrict__ Wb,
    bf16_t* __restrict__ Qn, bf16_t* __restrict__ Kn, bf16_t* __restrict__ Vt)
{
    __shared__ __align__(16) bf16_t aT0[128 * 32];
    __shared__ __align__(16) bf16_t bT0[128 * 32];
    __shared__ __align__(16) bf16_t aT1[128 * 32];
    __shared__ __align__(16) bf16_t bT1[128 * 32];
    const int bx = blockIdx.x, b = blockIdx.y;
    const int t = threadIdx.x, w = t >> 6, lane = t & 63;
    const int lid = lane & 15, quad = lane >> 4;
    const int wm = w >> 1, wn = w & 1;
    const float QSC = 0.125f * 1.44269504f;

    f32x4 acc[4][4] = {};

    if (bx < 96) {                        // Q or K job
        const bf16_t* A; const bf16_t* B; bf16_t* O; float scale;
        if (bx < 32) {
            int nt = bx >> 2, ct = bx & 3;
            A = Xc + (size_t)b * NT * CH + (size_t)nt * 128 * CH;
            B = Wb + (size_t)0 * CH * CH + (size_t)ct * 128 * CH;
            O = Qn + (size_t)b * NT * CH + (size_t)nt * 128 * CH + ct * 128;
            scale = QSC;
        } else {
            int j = bx - 32, nt = j >> 2, ct = j & 3;
            A = Xn + (size_t)b * 2 * NT * CH + (size_t)nt * 128 * CH;
            B = Wb + (size_t)1 * CH * CH + (size_t)ct * 128 * CH;
            O = Kn + (size_t)b * 2 * NT * CH + (size_t)nt * 128 * CH + ct * 128;
            scale = 1.0f;
        }
        gemm_core<false>(A, B, aT0, bT0, aT1, bT1, acc);
#pragma unroll
        for (int mi = 0; mi < 4; ++mi)
#pragma unroll
            for (int ni = 0; ni < 4; ++ni)
#pragma unroll
                for (int r = 0; r < 4; ++r) {
                    int n  = wm * 64 + mi * 16 + quad * 4 + r;
                    int co = wn * 64 + ni * 16 + lid;
                    O[(size_t)n * CH + co] = (bf16_t)(acc[mi][ni][r] * scale);
                }
    } else {                              // V job -> Vt[co][key]
        int j = bx - 96, nt = j >> 2, ct = j & 3;
        const bf16_t* A = Xn + (size_t)b * 2 * NT * CH + (size_t)nt * 128 * CH;
        const bf16_t* B = Wb + (size_t)2 * CH * CH + (size_t)ct * 128 * CH;
        bf16_t* O = Vt + (size_t)b * CH * 2 * NT + (size_t)ct * 128 * 2 * NT + nt * 128;
        gemm_core<true>(A, B, aT0, bT0, aT1, bT1, acc);
#pragma unroll
        for (int mi = 0; mi < 4; ++mi)
#pragma unroll
            for (int ni = 0; ni < 4; ++ni)
#pragma unroll
                for (int r = 0; r < 4; ++r) {
                    int co_l  = wm * 64 + mi * 16 + quad * 4 + r;
                    int key_l = wn * 64 + ni * 16 + lid;
                    O[(size_t)co_l * (2 * NT) + key_l] = (bf16_t)acc[mi][ni][r];
                }
    }
}

// ---------------------------------------------------------------------------
// attn v5a: coalesced global_load_lds staging of K/V, double-buffered, one
// barrier per k-tile; P in registers (cvt_pk+permlane); epilogue overlays.
// ---------------------------------------------------------------------------
__global__ __launch_bounds__(256, 2) void attn_kernel(
    const bf16_t* __restrict__ Qn, const bf16_t* __restrict__ Kn,
    const bf16_t* __restrict__ Vt, bf16_t* __restrict__ AOn)
{
    __shared__ __align__(16) char smem[65536];
    bf16_t* const kbuf0 = (bf16_t*)smem;             // [128][64] bf16
    bf16_t* const kbuf1 = (bf16_t*)(smem + 16384);
    bf16_t* const vbuf0 = (bf16_t*)(smem + 32768);   // [64][128] bf16
    bf16_t* const vbuf1 = (bf16_t*)(smem + 49152);
    // epilogue overlays (used only after the main loop's final barrier):
    float*  const scr_all = (float*)smem;            // 2 x 4352 f32 (34816B)
    bf16_t* const obuf    = (bf16_t*)(smem + 36864); // [128][72] bf16
    float*  const l_scr   = (float*)(smem + 55296);  // 128 f32

    const int t = threadIdx.x;
    const int w = t >> 6, lane = t & 63;
    const int wq = w >> 1, wk = w & 1;
    const int l31 = lane & 31, h = lane >> 5;

    // XCD-aware decode: all 8 q-tiles of one (b,h) share one XCD's L2.
    const int bid = blockIdx.x;
    const int xcd = bid & 7, ii = bid >> 3;
    const int grp = xcd * 8 + (ii >> 3);
    const int qt  = ii & 7;
    const int b = grp >> 3, hh = grp & 7;
    const int q0 = qt * 128;

    const bf16_t* Qb  = Qn + ((size_t)b * NT + q0) * CH + hh * HD;
    const bf16_t* Kb  = Kn + (size_t)b * 2 * NT * CH + hh * HD;
    const bf16_t* Vtb = Vt + ((size_t)b * CH + hh * HD) * (2 * NT);
    bf16_t* AOb = AOn + ((size_t)b * NT + q0) * CH + hh * HD;

#define STAGE_KV(kbn, kw, vw)                                                  \
    {                                                                          \
        _Pragma("unroll")                                                      \
        for (int i = 0; i < 4; ++i) {                                          \
            int ck = w * 64 + i * 256 + lane;                                  \
            int kr = ck >> 3, kg = ck & 7;                                     \
            gload16(Kb + (size_t)((kbn) + kr) * CH + ((kg ^ (kr & 7)) * 8),    \
                    (kw) + (w * 64 + i * 256) * 8);                            \
            int cv = ck;                                                       \
            int vr = cv >> 4, vg = cv & 15;                                    \
            gload16(Vtb + (size_t)vr * (2 * NT) + (kbn) + ((vg ^ (vr & 15)) * 8), \
                    (vw) + (w * 64 + i * 256) * 8);                            \
        }                                                                      \
    }

    // Q fragments: gathered once (one-time cost).
    const bf16_t* Qrow = Qb + (size_t)(wq * 64 + l31) * CH + h * 8;
    bf16x8 qf[2][4];
#pragma unroll
    for (int nf = 0; nf < 2; ++nf)
#pragma unroll
        for (int ks = 0; ks < 4; ++ks)
            qf[nf][ks] = *(const bf16x8*)(Qrow + (size_t)nf * 32 * CH + ks * 16);

    // prologue: stage tile 0 into buf 0
    STAGE_KV(0, kbuf0, vbuf0);
    __syncthreads();

    f32x16 o[2][2] = {};
    float lpart[2] = {0.f, 0.f};

    const int swk = l31 & 7;     // K read swizzle (row&7 == l31&7)
    const int swv = l31 & 15;    // V read swizzle (row&15 == l31&15)

    for (int kt = 0; kt < 16; ++kt) {
        const int cur = kt & 1;
        const bf16_t* const kr_buf = cur ? kbuf1 : kbuf0;
        const bf16_t* const vr_buf = cur ? vbuf1 : vbuf0;
        bf16_t* const kw_buf = cur ? kbuf0 : kbuf1;
        bf16_t* const vw_buf = cur ? vbuf0 : vbuf1;

        // issue next tile's staging first (lands during compute below)
        if (kt < 15)
            STAGE_KV((kt + 1) * 128, kw_buf, vw_buf);

#pragma unroll
        for (int mf = 0; mf < 2; ++mf) {
            // ---- K fragments from LDS (swizzled b128 reads) --------------
            const int krow = wk * 64 + mf * 32 + l31;
            bf16x8 kfm[4];
#pragma unroll
            for (int ks = 0; ks < 4; ++ks)
                kfm[ks] = *(const bf16x8*)(kr_buf + krow * 64 + (((ks * 2 + h) ^ swk) * 8));

            f32x16 s[2] = {};
            __builtin_amdgcn_s_setprio(1);
#pragma unroll
            for (int ks = 0; ks < 4; ++ks)
#pragma unroll
                for (int nf = 0; nf < 2; ++nf)
                    s[nf] = MFMA32(kfm[ks], qf[nf][ks], s[nf]);
            __builtin_amdgcn_s_setprio(0);

            // ---- softmax in registers -> PV B-fragments ------------------
            bf16x8 pfrag[2][2];                  // [nf][fi]
#pragma unroll
            for (int nf = 0; nf < 2; ++nf) {
                float p[16];
#pragma unroll
                for (int r = 0; r < 16; ++r) p[r] = EXP2(s[nf][r]);
                lpart[nf] += ((p[0] + p[1]) + (p[2] + p[3]))
                           + ((p[4] + p[5]) + (p[6] + p[7]))
                           + ((p[8] + p[9]) + (p[10] + p[11]))
                           + ((p[12] + p[13]) + (p[14] + p[15]));
                unsigned a0 = cvtpk(p[0], p[1]),   b0 = cvtpk(p[4], p[5]);
                unsigned a1 = cvtpk(p[2], p[3]),   b1 = cvtpk(p[6], p[7]);
                unsigned a2 = cvtpk(p[8], p[9]),   b2 = cvtpk(p[12], p[13]);
                unsigned a3 = cvtpk(p[10], p[11]), b3 = cvtpk(p[14], p[15]);
                plswap(a0, b0); plswap(a1, b1); plswap(a2, b2); plswap(a3, b3);
                u32x4 f0 = { a0, a1, b0, b1 };
                u32x4 f1 = { a2, a3, b2, b3 };
                pfrag[nf][0] = __builtin_bit_cast(bf16x8, f0);
                pfrag[nf][1] = __builtin_bit_cast(bf16x8, f1);
            }

            // ---- PV for this half (V fragments from LDS) ------------------
            __builtin_amdgcn_s_setprio(1);
#pragma unroll
            for (int fi = 0; fi < 2; ++fi) {
                const int ks = mf * 2 + fi;
                bf16x8 av[2];
#pragma unroll
                for (int df = 0; df < 2; ++df) {
                    int vrow = df * 32 + l31;
                    av[df] = *(const bf16x8*)(vr_buf + vrow * 128 +
                             (((wk * 8 + ks * 2 + h) ^ swv) * 8));
                }
#pragma unroll
                for (int df = 0; df < 2; ++df)
#pragma unroll
                    for (int nf = 0; nf < 2; ++nf)
                        o[df][nf] = MFMA32(av[df], pfrag[nf][fi], o[df][nf]);
            }
            __builtin_amdgcn_s_setprio(0);
        }
        __syncthreads();   // drains next-tile gloads; LDS bufs swap safely
    }
#undef STAGE_KV

    // ---- epilogue: combine wk halves, normalize, store --------------------
    float l2[2];
#pragma unroll
    for (int nf = 0; nf < 2; ++nf)
        l2[nf] = lpart[nf] + __shfl_xor(lpart[nf], 32);

    if (wk == 1) {
        float* scr = scr_all + wq * 4352;
#pragma unroll
        for (int df = 0; df < 2; ++df)
#pragma unroll
            for (int nf = 0; nf < 2; ++nf) {
                int qrow = nf * 32 + l31;
#pragma unroll
                for (int g = 0; g < 4; ++g) {
                    int d = df * 32 + 8 * g + 4 * h;
                    f32x4 v = { o[df][nf][4 * g + 0], o[df][nf][4 * g + 1],
                                o[df][nf][4 * g + 2], o[df][nf][4 * g + 3] };
                    *(f32x4*)(scr + qrow * 68 + d) = v;
                }
            }
        if (h == 0) {
            l_scr[wq * 64 + 0 * 32 + l31] = l2[0];
            l_scr[wq * 64 + 1 * 32 + l31] = l2[1];
        }
    }
    __syncthreads();

    if (wk == 0) {
        const float* scr = scr_all + wq * 4352;
        float inv[2];
#pragma unroll
        for (int nf = 0; nf < 2; ++nf)
            inv[nf] = 1.0f / (l2[nf] + l_scr[wq * 64 + nf * 32 + l31]);
#pragma unroll
        for (int df = 0; df < 2; ++df)
#pragma unroll
            for (int nf = 0; nf < 2; ++nf) {
                int qrow = nf * 32 + l31;
#pragma unroll
                for (int g = 0; g < 4; ++g) {
                    int d = df * 32 + 8 * g + 4 * h;
                    f32x4 part = *(const f32x4*)(scr + qrow * 68 + d);
                    bf16x4 ov = {
                        (bf16_t)((o[df][nf][4 * g + 0] + part.x) * inv[nf]),
                        (bf16_t)((o[df][nf][4 * g + 1] + part.y) * inv[nf]),
                        (bf16_t)((o[df][nf][4 * g + 2] + part.z) * inv[nf]),
                        (bf16_t)((o[df][nf][4 * g + 3] + part.w) * inv[nf]) };
                    int qg = wq * 64 + qrow;
                    *(bf16x4*)(obuf + qg * 72 + (d ^ (qg & 24))) = ov;
                }
            }
    }
    __syncthreads();

#pragma unroll
    for (int i = 0; i < 4; ++i) {
        int gid = t + i * 256;
        int qr = gid >> 3, c8 = (gid & 7) * 8;
        *(bf16x8*)(AOb + (size_t)qr * CH + c8) =
            *(const bf16x8*)(obuf + qr * 72 + (c8 ^ (qr & 24)));
    }
}

// ---------------------------------------------------------------------------
// proj: Z^T[b][co][n] = (AO @ Wo^T)^T + f_curr[b][co][n]  (fp32). grid (32, 8)
// Fused LN stats: block reduces its 128-co slab per n, atomicAdd sum/sumsq.
// ---------------------------------------------------------------------------
__global__ __launch_bounds__(256) void proj_kernel(
    const bf16_t* __restrict__ AOn, const bf16_t* __restrict__ Wb,
    const float* __restrict__ fc, float* __restrict__ Zt,
    float* __restrict__ Ssum, float* __restrict__ Ssq)
{
    __shared__ __align__(16) bf16_t aT0[128 * 32];
    __shared__ __align__(16) bf16_t bT0[128 * 32];
    __shared__ __align__(16) bf16_t aT1[128 * 32];
    __shared__ __align__(16) bf16_t bT1[128 * 32];
    const int bx = blockIdx.x, b = blockIdx.y;
    const int nt = bx >> 2, ct = bx & 3;
    const int t = threadIdx.x, w = t >> 6, lane = t & 63;
    const int lid = lane & 15, quad = lane >> 4;
    const int wm = w >> 1, wn = w & 1;

    const bf16_t* A = AOn + (size_t)b * NT * CH + (size_t)nt * 128 * CH;
    const bf16_t* B = Wb + (size_t)3 * CH * CH + (size_t)ct * 128 * CH;   // Wo

    f32x4 acc[4][4] = {};
    gemm_core<true>(A, B, aT0, bT0, aT1, bT1, acc);

    const size_t bofs = (size_t)b * CH * NT;
    float sP[4] = {0.f, 0.f, 0.f, 0.f}, qP[4] = {0.f, 0.f, 0.f, 0.f};
#pragma unroll
    for (int mi = 0; mi < 4; ++mi)
#pragma unroll
        for (int ni = 0; ni < 4; ++ni)
#pragma unroll
            for (int r = 0; r < 4; ++r) {
                int co_l = wm * 64 + mi * 16 + quad * 4 + r;
                int n_l  = wn * 64 + ni * 16 + lid;
                size_t idx = bofs + (size_t)(ct * 128 + co_l) * NT + nt * 128 + n_l;
                float z = acc[mi][ni][r] + fc[idx];
                Zt[idx] = z;
                sP[ni] += z;
                qP[ni] += z * z;
            }
    // reduce over quad (co sub-blocks) within wave
#pragma unroll
    for (int ni = 0; ni < 4; ++ni) {
        sP[ni] += __shfl_xor(sP[ni], 16);  sP[ni] += __shfl_xor(sP[ni], 32);
        qP[ni] += __shfl_xor(qP[ni], 16);  qP[ni] += __shfl_xor(qP[ni], 32);
    }
    __syncthreads();                      // all frag reads of LDS done
    float* sRed = (float*)aT0;            // 256 f32
    float* qRed = sRed + 256;
    if (quad == 0) {
#pragma unroll
        for (int ni = 0; ni < 4; ++ni) {
            sRed[w * 64 + ni * 16 + lid] = sP[ni];
            qRed[w * 64 + ni * 16 + lid] = qP[ni];
        }
    }
    __syncthreads();
    if (t < 128) {                        // n_l = t; waves w=wn and w=2+wn
        float s = sRed[t] + sRed[128 + t];
        float q = qRed[t] + qRed[128 + t];
        atomicAdd(&Ssum[(size_t)b * NT + nt * 128 + t], s);
        atomicAdd(&Ssq [(size_t)b * NT + nt * 128 + t], q);
    }
}

// ---------------------------------------------------------------------------
// apply: out[b][co][n] = (z - mu[n]) * rs[n] * gamma[co] + beta[co].
// mu/rs computed inline from fused sum/sumsq.
// ---------------------------------------------------------------------------
__global__ __launch_bounds__(256) void apply_kernel(
    const float* __restrict__ Zt, const float* __restrict__ Ssum,
    const float* __restrict__ Ssq, const float* __restrict__ gamma,
    const float* __restrict__ beta, float* __restrict__ out)
{
    const int row = blockIdx.x;           // b*512 + co
    const int co = row & 511, b = row >> 9;
    const int t = threadIdx.x;
    const float g = gamma[co], be = beta[co];
    const size_t base = (size_t)row * NT + t * 4;
    f32x4 z  = *(const f32x4*)(Zt + base);
    f32x4 S  = *(const f32x4*)(Ssum + (size_t)b * NT + t * 4);
    f32x4 Q2 = *(const f32x4*)(Ssq  + (size_t)b * NT + t * 4);
    f32x4 o;
#pragma unroll
    for (int c = 0; c < 4; ++c) {
        float mu  = S[c] * (1.0f / 512.0f);
        float var = Q2[c] * (1.0f / 512.0f) - mu * mu;
        float rs  = rsqrtf(var + 1e-5f);
        o[c] = (z[c] - mu) * rs * g + be;
    }
    *(f32x4*)(out + base) = o;
}

// ---------------------------------------------------------------------------
extern "C" void kernel_launch(void* const* d_in, const int* in_sizes, int n_in,
                              void* d_out, int out_size, void* d_ws, size_t ws_size,
                              hipStream_t stream)
{
    (void)in_sizes; (void)n_in; (void)out_size; (void)ws_size;
    const float* fc    = (const float*)d_in[0];
    const float* fp    = (const float*)d_in[1];
    const float* fn    = (const float*)d_in[2];
    const float* Wq    = (const float*)d_in[3];
    const float* Wk    = (const float*)d_in[4];
    const float* Wv    = (const float*)d_in[5];
    const float* Wo    = (const float*)d_in[6];
    const float* gamma = (const float*)d_in[7];
    const float* beta  = (const float*)d_in[8];
    float* out = (float*)d_out;

    char* ws = (char*)d_ws;
    bf16_t* Xn  = (bf16_t*)(ws);
    bf16_t* Qn  = (bf16_t*)(ws + 16777216);
    bf16_t* Kn  = (bf16_t*)(ws + 25165824);
    bf16_t* Xc  = (bf16_t*)(ws + 41943040);
    bf16_t* AOn = Xc;
    bf16_t* Vt  = (bf16_t*)(ws + 50331648);
    bf16_t* Wb  = (bf16_t*)(ws + 67108864);
    float*  Ssum = (float*)(ws + 69206016);
    float*  Ssq  = (float*)(ws + 69238784);
    float*  Zt  = (float*)(ws);

    prep_kernel<<<dim3(128, 24), 256, 0, stream>>>(fc, fp, fn, Xc, Xn);
    wcvt_kernel<<<dim3(256, 4), 256, 0, stream>>>(Wq, Wk, Wv, Wo, Wb, Ssum);
    qkv_kernel<<<dim3(160, 8), 256, 0, stream>>>(Xc, Xn, Wb, Qn, Kn, Vt);
    attn_kernel<<<dim3(512), 256, 0, stream>>>(Qn, Kn, Vt, AOn);
    proj_kernel<<<dim3(32, 8), 256, 0, stream>>>(AOn, Wb, fc, Zt, Ssum, Ssq);
    apply_kernel<<<4096, 256, 0, stream>>>(Zt, Ssum, Ssq, gamma, beta, out);
}